// Round 8
// baseline (1460.545 us; speedup 1.0000x reference)
//
#include <hip/hip_runtime.h>
#include <math.h>

// ---- problem geometry ----
#define T_IN    8192
#define T1      8183        // conv1 'valid' output length
#define LP      4087        // after MaxPool1d(2)
#define NFLAT   523136      // 128 * 4087
#define NFLAT4  130784      // NFLAT / 4
#define NDIM    10000
#define RSTRIDE 8208        // padded row stride for r1
#define F_OFF   (64*RSTRIDE)     // start of flat[] in ws (floats)
#define P_OFF   (F_OFF + NFLAT)  // start of partials[128][32] in ws
#define NCHUNK  32
#define CHUNK4  4087        // float4 per chunk (NFLAT4 / 32)

typedef __attribute__((ext_vector_type(4))) float f4;

// =====================================================================
// Kernel 1: conv1 (round-3 exact)
// =====================================================================
__global__ __launch_bounds__(256) void k1_conv1(
    const float* __restrict__ sig, const float* __restrict__ w1,
    const float* __restrict__ b1, float* __restrict__ r1)
{
  __shared__ float4 srow[266];
  const int tid = threadIdx.x;
  const int t0b = blockIdx.x * 256;
  for (int idx = tid; idx < 266; idx += 256) {
    int t = t0b + idx;
    float4 v = make_float4(0.f, 0.f, 0.f, 0.f);
    if (t < T_IN) v = ((const float4*)sig)[t];
    srow[idx] = v;
  }
  __syncthreads();
  const int t = t0b + tid;
  float s[40];
#pragma unroll
  for (int k = 0; k < 10; ++k) {
    float4 v = srow[tid + k];
    s[4*k+0] = v.x; s[4*k+1] = v.y; s[4*k+2] = v.z; s[4*k+3] = v.w;
  }
  const int c0 = blockIdx.y * 8;
  for (int c = c0; c < c0 + 8; ++c) {
    const float* __restrict__ w = w1 + c * 40;
    float a0 = 0.f, a1 = 0.f, a2 = 0.f, a3 = 0.f;
#pragma unroll
    for (int k = 0; k < 10; ++k) {
      a0 = fmaf(s[4*k+0], w[k     ], a0);
      a1 = fmaf(s[4*k+1], w[10 + k], a1);
      a2 = fmaf(s[4*k+2], w[20 + k], a2);
      a3 = fmaf(s[4*k+3], w[30 + k], a3);
    }
    float v = fmaxf((a0 + a1) + (a2 + a3) + b1[c], 0.f);
    if (t < T1) r1[c * RSTRIDE + t] = v;
  }
}

// =====================================================================
// k2 VARIANT 1 x16: round-3 exact body (control).
// grid (32,16): 2 ch/wave, f-window via 4 x ds_read_b128.
// =====================================================================
__global__ __launch_bounds__(256) void k2v1_p16(
    const float* __restrict__ r1, const float* __restrict__ w2,
    const float* __restrict__ b2, float* __restrict__ flat)
{
  __shared__ float tile[16][272];
  const int tid  = threadIdx.x;
  const int lane = tid & 63;
  const int wave = tid >> 6;
  const int t0b  = blockIdx.x * 256;
  const int o0   = __builtin_amdgcn_readfirstlane(blockIdx.y * 8 + wave * 2);
  const int t0   = t0b + lane * 4;

  for (int rep = 0; rep < 16; ++rep) {
    float acc[2][4];
#pragma unroll
    for (int a = 0; a < 2; ++a)
#pragma unroll
      for (int b = 0; b < 4; ++b) acc[a][b] = 0.f;

    for (int cc = 0; cc < 4; ++cc) {
      __syncthreads();
#pragma unroll
      for (int rr = 0; rr < 4; ++rr) {
        int row = wave * 4 + rr;
        const float4* src = (const float4*)(r1 + (cc * 16 + row) * RSTRIDE + t0b);
        ((float4*)&tile[row][0])[lane] = src[lane];
        if (lane < 4) ((float4*)&tile[row][0])[64 + lane] = src[64 + lane];
      }
      __syncthreads();

      for (int cr = 0; cr < 16; ++cr) {
        float f[16];
        const float4* tr4 = (const float4*)&tile[cr][0];
#pragma unroll
        for (int q = 0; q < 4; ++q) {
          float4 v = tr4[lane + q];
          f[4*q+0] = v.x; f[4*q+1] = v.y; f[4*q+2] = v.z; f[4*q+3] = v.w;
        }
        const int c = cc * 16 + cr;
#pragma unroll
        for (int oo = 0; oo < 2; ++oo) {
          const float* __restrict__ w = w2 + ((o0 + oo) * 64 + c) * 10;
#pragma unroll
          for (int k = 0; k < 10; ++k) {
            float wv = w[k];
#pragma unroll
            for (int tt = 0; tt < 4; ++tt)
              acc[oo][tt] = fmaf(wv, f[k + tt], acc[oo][tt]);
          }
        }
      }
    }

#pragma unroll
    for (int oo = 0; oo < 2; ++oo) {
      const int o = o0 + oo;
      const float bias = b2[o];
#pragma unroll
      for (int lt = 0; lt < 2; ++lt) {
        float a = acc[oo][2*lt]     + bias;
        float b = acc[oo][2*lt + 1] + bias;
        float m = fmaxf(fmaxf(a, b), 0.f);
        int l = t0 / 2 + lt;
        if (l < LP) flat[o * LP + l] = m;
      }
    }
  }
}

// =====================================================================
// k2 VARIANT 2 x16: 4 ch/wave, grid (32,8) -> HALF the total LDS
// instructions/traffic per FLOP (tests the traffic theory).
// Same per-output accumulation order as v1 (bitwise identical flat[]).
// =====================================================================
__global__ __launch_bounds__(256) void k2v2_p16(
    const float* __restrict__ r1, const float* __restrict__ w2,
    const float* __restrict__ b2, float* __restrict__ flat)
{
  __shared__ float tile[16][272];
  const int tid  = threadIdx.x;
  const int lane = tid & 63;
  const int wave = tid >> 6;
  const int t0b  = blockIdx.x * 256;
  const int o0   = __builtin_amdgcn_readfirstlane(blockIdx.y * 16 + wave * 4);
  const int t0   = t0b + lane * 4;

  for (int rep = 0; rep < 16; ++rep) {
    float acc[4][4];
#pragma unroll
    for (int a = 0; a < 4; ++a)
#pragma unroll
      for (int b = 0; b < 4; ++b) acc[a][b] = 0.f;

    for (int cc = 0; cc < 4; ++cc) {
      __syncthreads();
#pragma unroll
      for (int rr = 0; rr < 4; ++rr) {
        int row = wave * 4 + rr;
        const float4* src = (const float4*)(r1 + (cc * 16 + row) * RSTRIDE + t0b);
        ((float4*)&tile[row][0])[lane] = src[lane];
        if (lane < 4) ((float4*)&tile[row][0])[64 + lane] = src[64 + lane];
      }
      __syncthreads();

      for (int cr = 0; cr < 16; ++cr) {
        float f[16];
        const float4* tr4 = (const float4*)&tile[cr][0];
#pragma unroll
        for (int q = 0; q < 4; ++q) {
          float4 v = tr4[lane + q];
          f[4*q+0] = v.x; f[4*q+1] = v.y; f[4*q+2] = v.z; f[4*q+3] = v.w;
        }
        const int c = cc * 16 + cr;
#pragma unroll
        for (int oo = 0; oo < 4; ++oo) {
          const float* __restrict__ w = w2 + ((o0 + oo) * 64 + c) * 10;
#pragma unroll
          for (int k = 0; k < 10; ++k) {
            float wv = w[k];
#pragma unroll
            for (int tt = 0; tt < 4; ++tt)
              acc[oo][tt] = fmaf(wv, f[k + tt], acc[oo][tt]);
          }
        }
      }
    }

#pragma unroll
    for (int oo = 0; oo < 4; ++oo) {
      const int o = o0 + oo;
      const float bias = b2[o];
#pragma unroll
      for (int lt = 0; lt < 2; ++lt) {
        float a = acc[oo][2*lt]     + bias;
        float b = acc[oo][2*lt + 1] + bias;
        float m = fmaxf(fmaxf(a, b), 0.f);
        int l = t0 / 2 + lt;
        if (l < LP) flat[o * LP + l] = m;
      }
    }
  }
}

// =====================================================================
// k2 VARIANT 3 x16: identical to v1 EXCEPT f-window read as 7 x
// ds_read_b64 (float2, floats 4l..4l+13) instead of 4 x ds_read_b128
// (tests the access-width / phase-conflict theory).
// =====================================================================
__global__ __launch_bounds__(256) void k2v3_p16(
    const float* __restrict__ r1, const float* __restrict__ w2,
    const float* __restrict__ b2, float* __restrict__ flat)
{
  __shared__ float tile[16][272];
  const int tid  = threadIdx.x;
  const int lane = tid & 63;
  const int wave = tid >> 6;
  const int t0b  = blockIdx.x * 256;
  const int o0   = __builtin_amdgcn_readfirstlane(blockIdx.y * 8 + wave * 2);
  const int t0   = t0b + lane * 4;

  for (int rep = 0; rep < 16; ++rep) {
    float acc[2][4];
#pragma unroll
    for (int a = 0; a < 2; ++a)
#pragma unroll
      for (int b = 0; b < 4; ++b) acc[a][b] = 0.f;

    for (int cc = 0; cc < 4; ++cc) {
      __syncthreads();
#pragma unroll
      for (int rr = 0; rr < 4; ++rr) {
        int row = wave * 4 + rr;
        const float4* src = (const float4*)(r1 + (cc * 16 + row) * RSTRIDE + t0b);
        ((float4*)&tile[row][0])[lane] = src[lane];
        if (lane < 4) ((float4*)&tile[row][0])[64 + lane] = src[64 + lane];
      }
      __syncthreads();

      for (int cr = 0; cr < 16; ++cr) {
        float f[14];
        const float2* tr2 = (const float2*)&tile[cr][0];
#pragma unroll
        for (int q = 0; q < 7; ++q) {
          float2 v = tr2[2 * lane + q];      // floats 4l+2q, 4l+2q+1
          f[2*q+0] = v.x; f[2*q+1] = v.y;
        }
        const int c = cc * 16 + cr;
#pragma unroll
        for (int oo = 0; oo < 2; ++oo) {
          const float* __restrict__ w = w2 + ((o0 + oo) * 64 + c) * 10;
#pragma unroll
          for (int k = 0; k < 10; ++k) {
            float wv = w[k];
#pragma unroll
            for (int tt = 0; tt < 4; ++tt)
              acc[oo][tt] = fmaf(wv, f[k + tt], acc[oo][tt]);
          }
        }
      }
    }

#pragma unroll
    for (int oo = 0; oo < 2; ++oo) {
      const int o = o0 + oo;
      const float bias = b2[o];
#pragma unroll
      for (int lt = 0; lt < 2; ++lt) {
        float a = acc[oo][2*lt]     + bias;
        float b = acc[oo][2*lt + 1] + bias;
        float m = fmaxf(fmaxf(a, b), 0.f);
        int l = t0 / 2 + lt;
        if (l < LP) flat[o * LP + l] = m;
      }
    }
  }
}

// =====================================================================
// Kernel 3: linear (round-3 exact; 37.5 us/pass known)
// =====================================================================
__global__ __launch_bounds__(256) void k3_linear(
    const float* __restrict__ lw, const float* __restrict__ flat,
    float* __restrict__ partials)
{
  const int tid = threadIdx.x;
  const int ch  = blockIdx.x;
  const int j0  = blockIdx.y * 4;
  const f4* __restrict__ fl = (const f4*)flat + (size_t)ch * CHUNK4;

  float r[4];
#pragma unroll
  for (int ph = 0; ph < 2; ++ph) {
    const int j = j0 + 2 * ph;
    const f4* __restrict__ p0 = (const f4*)lw + (size_t)(j + 0) * NFLAT4 + (size_t)ch * CHUNK4;
    const f4* __restrict__ p1 = (const f4*)lw + (size_t)(j + 1) * NFLAT4 + (size_t)ch * CHUNK4;
    f4 a0 = (f4)0.f, a1 = (f4)0.f;
    for (int i = tid; i < CHUNK4; i += 256) {
      f4 x  = fl[i];
      f4 w0 = p0[i];
      f4 w1 = p1[i];
      a0.x = fmaf(x.x, w0.x, a0.x); a0.y = fmaf(x.y, w0.y, a0.y);
      a0.z = fmaf(x.z, w0.z, a0.z); a0.w = fmaf(x.w, w0.w, a0.w);
      a1.x = fmaf(x.x, w1.x, a1.x); a1.y = fmaf(x.y, w1.y, a1.y);
      a1.z = fmaf(x.z, w1.z, a1.z); a1.w = fmaf(x.w, w1.w, a1.w);
    }
    r[2*ph + 0] = (a0.x + a0.y) + (a0.z + a0.w);
    r[2*ph + 1] = (a1.x + a1.y) + (a1.z + a1.w);
  }

  __shared__ float red[4][257];
#pragma unroll
  for (int j = 0; j < 4; ++j) red[j][tid] = r[j];
  for (int off = 128; off > 0; off >>= 1) {
    __syncthreads();
    if (tid < off) {
#pragma unroll
      for (int j = 0; j < 4; ++j) red[j][tid] += red[j][tid + off];
    }
  }
  if (tid == 0) {
#pragma unroll
    for (int j = 0; j < 4; ++j) partials[(j0 + j) * NCHUNK + ch] = red[j][0];
  }
}

// =====================================================================
// Kernel 4: finalize (round-3 exact; ~3 us known)
// =====================================================================
__global__ __launch_bounds__(64) void k4_hdc(
    const float* __restrict__ partials, const float* __restrict__ lin_b,
    const float* __restrict__ hdc_w, const float* __restrict__ hdc_b,
    const float* __restrict__ feat, const int* __restrict__ feat_idx,
    const float* __restrict__ feat_w, const float* __restrict__ feat_b,
    float* __restrict__ out)
{
  __shared__ __align__(16) float y[128];
  __shared__ float fv[18];
  const int tid = threadIdx.x;
#pragma unroll
  for (int half = 0; half < 2; ++half) {
    const int row = tid + half * 64;
    float s = lin_b[row];
    const float* p = partials + row * NCHUNK;
#pragma unroll
    for (int c = 0; c < NCHUNK; ++c) s += p[c];
    y[row] = fmaxf(s, 0.f);
  }
  if (tid < 18) fv[tid] = feat[feat_idx[tid]];
  __syncthreads();

  const int d = blockIdx.x * 64 + tid;
  if (d >= NDIM) return;

  const float4* __restrict__ hw = (const float4*)(hdc_w + d * 128);
  const float4* __restrict__ yy = (const float4*)y;
  float4 ac = make_float4(0, 0, 0, 0);
#pragma unroll
  for (int q = 0; q < 32; ++q) {
    float4 w = hw[q];
    float4 v = yy[q];
    ac.x = fmaf(w.x, v.x, ac.x); ac.y = fmaf(w.y, v.y, ac.y);
    ac.z = fmaf(w.z, v.z, ac.z); ac.w = fmaf(w.w, v.w, ac.w);
  }
  const float proj = (ac.x + ac.y) + (ac.z + ac.w);
  const float sample_hv = cosf(proj + hdc_b[d]) * sinf(proj);

  float h[18];
#pragma unroll
  for (int i = 0; i < 18; ++i) {
    float fp = fv[i] * feat_w[i * NDIM + d];
    h[i] = cosf(fp + feat_b[i * NDIM + d]) * sinf(fp);
  }
  const float feat_hv =
      (h[14] + h[11]) * h[16]
    * (h[4] + h[8] + h[6] + h[1] + h[5] + h[12] + h[17])
    * h[13] * (h[15] + h[2]) * h[3]
    * h[0] * h[10] * h[7] * h[9];

  const float comb = sample_hv + feat_hv;
  out[d] = comb > 0.f ? 1.f : -1.f;
}

// =====================================================================
extern "C" void kernel_launch(void* const* d_in, const int* in_sizes, int n_in,
                              void* d_out, int out_size, void* d_ws, size_t ws_size,
                              hipStream_t stream)
{
  const float* sig  = (const float*)d_in[0];
  const float* feat = (const float*)d_in[1];
  const float* w1   = (const float*)d_in[2];
  const float* b1   = (const float*)d_in[3];
  const float* w2   = (const float*)d_in[4];
  const float* b2   = (const float*)d_in[5];
  const float* lw   = (const float*)d_in[6];
  const float* lb   = (const float*)d_in[7];
  const float* hw   = (const float*)d_in[8];
  const float* hb   = (const float*)d_in[9];
  const float* fw   = (const float*)d_in[10];
  const float* fb   = (const float*)d_in[11];
  const int*   fidx = (const int*)d_in[12];
  float* out = (float*)d_out;
  float* ws  = (float*)d_ws;

  float* r1       = ws;              // [64][RSTRIDE]
  float* flat     = ws + F_OFF;      // [NFLAT]
  float* partials = ws + P_OFF;      // [128][NCHUNK]

  k1_conv1 <<<dim3(32, 8),  256, 0, stream>>>(sig, w1, b1, r1);
  k2v1_p16 <<<dim3(32, 16), 256, 0, stream>>>(r1, w2, b2, flat);
  k2v2_p16 <<<dim3(32, 8),  256, 0, stream>>>(r1, w2, b2, flat);
  k2v3_p16 <<<dim3(32, 16), 256, 0, stream>>>(r1, w2, b2, flat);
  k3_linear<<<dim3(32, 32), 256, 0, stream>>>(lw, flat, partials);
  k4_hdc   <<<dim3(157, 1), 64,  0, stream>>>(partials, lb, hw, hb,
                                              feat, fidx, fw, fb, out);
}

// Round 9
// 345.038 us; speedup vs baseline: 4.2330x; 4.2330x over previous
//
#include <hip/hip_runtime.h>
#include <math.h>

// ---- problem geometry ----
#define T_IN    8192
#define T1      8183        // conv1 'valid' output length
#define LP      4087        // after MaxPool1d(2)
#define NFLAT   523136      // 128 * 4087
#define NFLAT4  130784      // NFLAT / 4
#define NDIM    10000
#define RSTRIDE 8208        // padded row stride for r1
#define F_OFF   (64*RSTRIDE)     // start of flat[] in ws (floats)
#define P_OFF   (F_OFF + NFLAT)  // start of partials[128][32] in ws
#define NCHUNK  32
#define CHUNK4  4087        // float4 per chunk (NFLAT4 / 32)
#define NTROWS  32          // k3: rows 0..31 NT-streamed (67 MB); 32..127 MALL-resident (201 MB)

typedef __attribute__((ext_vector_type(4))) float f4;

// =====================================================================
// Kernel 1: conv1 (round-3 exact)
// =====================================================================
__global__ __launch_bounds__(256) void k1_conv1(
    const float* __restrict__ sig, const float* __restrict__ w1,
    const float* __restrict__ b1, float* __restrict__ r1)
{
  __shared__ float4 srow[266];
  const int tid = threadIdx.x;
  const int t0b = blockIdx.x * 256;
  for (int idx = tid; idx < 266; idx += 256) {
    int t = t0b + idx;
    float4 v = make_float4(0.f, 0.f, 0.f, 0.f);
    if (t < T_IN) v = ((const float4*)sig)[t];
    srow[idx] = v;
  }
  __syncthreads();
  const int t = t0b + tid;
  float s[40];
#pragma unroll
  for (int k = 0; k < 10; ++k) {
    float4 v = srow[tid + k];
    s[4*k+0] = v.x; s[4*k+1] = v.y; s[4*k+2] = v.z; s[4*k+3] = v.w;
  }
  const int c0 = blockIdx.y * 8;
  for (int c = c0; c < c0 + 8; ++c) {
    const float* __restrict__ w = w1 + c * 40;
    float a0 = 0.f, a1 = 0.f, a2 = 0.f, a3 = 0.f;
#pragma unroll
    for (int k = 0; k < 10; ++k) {
      a0 = fmaf(s[4*k+0], w[k     ], a0);
      a1 = fmaf(s[4*k+1], w[10 + k], a1);
      a2 = fmaf(s[4*k+2], w[20 + k], a2);
      a3 = fmaf(s[4*k+3], w[30 + k], a3);
    }
    float v = fmaxf((a0 + a1) + (a2 + a3) + b1[c], 0.f);
    if (t < T1) r1[c * RSTRIDE + t] = v;
  }
}

// =====================================================================
// Kernel 2 NEW (PROBE x16): conv2+pool with NO LDS. r1 (2.1 MB) is
// L2-resident; each lane reads its 16-float window via 4 overlapping
// coalesced dwordx4 loads (L1 absorbs the 4x within-wave overlap).
// Same (o0,t0) mapping and c/k accumulation order as round-3 v1 ->
// bitwise-identical flat[]. Expect SQ_LDS_BANK_CONFLICT == 0.
// =====================================================================
__global__ __launch_bounds__(256) void k2n_p16(
    const float* __restrict__ r1, const float* __restrict__ w2,
    const float* __restrict__ b2, float* __restrict__ flat)
{
  const int tid  = threadIdx.x;
  const int lane = tid & 63;
  const int wave = tid >> 6;
  const int t0b  = blockIdx.x * 256;
  const int o0   = __builtin_amdgcn_readfirstlane(blockIdx.y * 8 + wave * 2);
  const int t0   = t0b + lane * 4;

  for (int rep = 0; rep < 16; ++rep) {
    float acc[2][4];
#pragma unroll
    for (int a = 0; a < 2; ++a)
#pragma unroll
      for (int b = 0; b < 4; ++b) acc[a][b] = 0.f;

    for (int c = 0; c < 64; ++c) {
      const f4* __restrict__ p = (const f4*)(r1 + c * RSTRIDE + t0b) + lane;
      f4 v0 = p[0];          // floats t0 .. t0+3   (consecutive lanes -> coalesced)
      f4 v1 = p[1];          // t0+4 .. t0+7
      f4 v2 = p[2];          // t0+8 .. t0+11
      f4 v3 = p[3];          // t0+12.. t0+15 (f[13..15] dead; reads stay in padded row)
      float f[16];
      f[0]=v0.x; f[1]=v0.y; f[2]=v0.z; f[3]=v0.w;
      f[4]=v1.x; f[5]=v1.y; f[6]=v1.z; f[7]=v1.w;
      f[8]=v2.x; f[9]=v2.y; f[10]=v2.z; f[11]=v2.w;
      f[12]=v3.x; f[13]=v3.y; f[14]=v3.z; f[15]=v3.w;
#pragma unroll
      for (int oo = 0; oo < 2; ++oo) {
        const float* __restrict__ w = w2 + ((o0 + oo) * 64 + c) * 10; // wave-uniform s_loads
#pragma unroll
        for (int k = 0; k < 10; ++k) {
          float wv = w[k];
#pragma unroll
          for (int tt = 0; tt < 4; ++tt)
            acc[oo][tt] = fmaf(wv, f[k + tt], acc[oo][tt]);
        }
      }
    }

#pragma unroll
    for (int oo = 0; oo < 2; ++oo) {
      const int o = o0 + oo;
      const float bias = b2[o];
#pragma unroll
      for (int lt = 0; lt < 2; ++lt) {
        float a = acc[oo][2*lt]     + bias;
        float b = acc[oo][2*lt + 1] + bias;
        float m = fmaxf(fmaxf(a, b), 0.f);
        int l = t0 / 2 + lt;
        if (l < LP) flat[o * LP + l] = m;
      }
    }
  }
}

// =====================================================================
// Kernel 3: linear with NT-SPLIT. Rows 0..NTROWS-1 (67 MB) use
// nontemporal loads (no MALL allocation); rows NTROWS..127 (201 MB)
// plain loads -> stay MALL-resident across graph replays. Accumulation
// order identical in both arms (bit-exact vs round-3).
// =====================================================================
__global__ __launch_bounds__(256) void k3_linear_nt(
    const float* __restrict__ lw, const float* __restrict__ flat,
    float* __restrict__ partials)
{
  const int tid = threadIdx.x;
  const int ch  = blockIdx.x;
  const int j0  = blockIdx.y * 4;
  const f4* __restrict__ fl = (const f4*)flat + (size_t)ch * CHUNK4;
  const bool nt = (j0 < NTROWS);   // block-uniform

  float r[4];
#pragma unroll
  for (int ph = 0; ph < 2; ++ph) {
    const int j = j0 + 2 * ph;
    const f4* __restrict__ p0 = (const f4*)lw + (size_t)(j + 0) * NFLAT4 + (size_t)ch * CHUNK4;
    const f4* __restrict__ p1 = (const f4*)lw + (size_t)(j + 1) * NFLAT4 + (size_t)ch * CHUNK4;
    f4 a0 = (f4)0.f, a1 = (f4)0.f;
    if (nt) {
      for (int i = tid; i < CHUNK4; i += 256) {
        f4 x  = fl[i];
        f4 w0 = __builtin_nontemporal_load(p0 + i);
        f4 w1 = __builtin_nontemporal_load(p1 + i);
        a0.x = fmaf(x.x, w0.x, a0.x); a0.y = fmaf(x.y, w0.y, a0.y);
        a0.z = fmaf(x.z, w0.z, a0.z); a0.w = fmaf(x.w, w0.w, a0.w);
        a1.x = fmaf(x.x, w1.x, a1.x); a1.y = fmaf(x.y, w1.y, a1.y);
        a1.z = fmaf(x.z, w1.z, a1.z); a1.w = fmaf(x.w, w1.w, a1.w);
      }
    } else {
      for (int i = tid; i < CHUNK4; i += 256) {
        f4 x  = fl[i];
        f4 w0 = p0[i];
        f4 w1 = p1[i];
        a0.x = fmaf(x.x, w0.x, a0.x); a0.y = fmaf(x.y, w0.y, a0.y);
        a0.z = fmaf(x.z, w0.z, a0.z); a0.w = fmaf(x.w, w0.w, a0.w);
        a1.x = fmaf(x.x, w1.x, a1.x); a1.y = fmaf(x.y, w1.y, a1.y);
        a1.z = fmaf(x.z, w1.z, a1.z); a1.w = fmaf(x.w, w1.w, a1.w);
      }
    }
    r[2*ph + 0] = (a0.x + a0.y) + (a0.z + a0.w);
    r[2*ph + 1] = (a1.x + a1.y) + (a1.z + a1.w);
  }

  __shared__ float red[4][257];
#pragma unroll
  for (int j = 0; j < 4; ++j) red[j][tid] = r[j];
  for (int off = 128; off > 0; off >>= 1) {
    __syncthreads();
    if (tid < off) {
#pragma unroll
      for (int j = 0; j < 4; ++j) red[j][tid] += red[j][tid + off];
    }
  }
  if (tid == 0) {
#pragma unroll
    for (int j = 0; j < 4; ++j) partials[(j0 + j) * NCHUNK + ch] = red[j][0];
  }
}

// =====================================================================
// Kernel 4: finalize (round-3 exact)
// =====================================================================
__global__ __launch_bounds__(64) void k4_hdc(
    const float* __restrict__ partials, const float* __restrict__ lin_b,
    const float* __restrict__ hdc_w, const float* __restrict__ hdc_b,
    const float* __restrict__ feat, const int* __restrict__ feat_idx,
    const float* __restrict__ feat_w, const float* __restrict__ feat_b,
    float* __restrict__ out)
{
  __shared__ __align__(16) float y[128];
  __shared__ float fv[18];
  const int tid = threadIdx.x;
#pragma unroll
  for (int half = 0; half < 2; ++half) {
    const int row = tid + half * 64;
    float s = lin_b[row];
    const float* p = partials + row * NCHUNK;
#pragma unroll
    for (int c = 0; c < NCHUNK; ++c) s += p[c];
    y[row] = fmaxf(s, 0.f);
  }
  if (tid < 18) fv[tid] = feat[feat_idx[tid]];
  __syncthreads();

  const int d = blockIdx.x * 64 + tid;
  if (d >= NDIM) return;

  const float4* __restrict__ hw = (const float4*)(hdc_w + d * 128);
  const float4* __restrict__ yy = (const float4*)y;
  float4 ac = make_float4(0, 0, 0, 0);
#pragma unroll
  for (int q = 0; q < 32; ++q) {
    float4 w = hw[q];
    float4 v = yy[q];
    ac.x = fmaf(w.x, v.x, ac.x); ac.y = fmaf(w.y, v.y, ac.y);
    ac.z = fmaf(w.z, v.z, ac.z); ac.w = fmaf(w.w, v.w, ac.w);
  }
  const float proj = (ac.x + ac.y) + (ac.z + ac.w);
  const float sample_hv = cosf(proj + hdc_b[d]) * sinf(proj);

  float h[18];
#pragma unroll
  for (int i = 0; i < 18; ++i) {
    float fp = fv[i] * feat_w[i * NDIM + d];
    h[i] = cosf(fp + feat_b[i * NDIM + d]) * sinf(fp);
  }
  const float feat_hv =
      (h[14] + h[11]) * h[16]
    * (h[4] + h[8] + h[6] + h[1] + h[5] + h[12] + h[17])
    * h[13] * (h[15] + h[2]) * h[3]
    * h[0] * h[10] * h[7] * h[9];

  const float comb = sample_hv + feat_hv;
  out[d] = comb > 0.f ? 1.f : -1.f;
}

// =====================================================================
extern "C" void kernel_launch(void* const* d_in, const int* in_sizes, int n_in,
                              void* d_out, int out_size, void* d_ws, size_t ws_size,
                              hipStream_t stream)
{
  const float* sig  = (const float*)d_in[0];
  const float* feat = (const float*)d_in[1];
  const float* w1   = (const float*)d_in[2];
  const float* b1   = (const float*)d_in[3];
  const float* w2   = (const float*)d_in[4];
  const float* b2   = (const float*)d_in[5];
  const float* lw   = (const float*)d_in[6];
  const float* lb   = (const float*)d_in[7];
  const float* hw   = (const float*)d_in[8];
  const float* hb   = (const float*)d_in[9];
  const float* fw   = (const float*)d_in[10];
  const float* fb   = (const float*)d_in[11];
  const int*   fidx = (const int*)d_in[12];
  float* out = (float*)d_out;
  float* ws  = (float*)d_ws;

  float* r1       = ws;              // [64][RSTRIDE]
  float* flat     = ws + F_OFF;      // [NFLAT]
  float* partials = ws + P_OFF;      // [128][NCHUNK]

  k1_conv1    <<<dim3(32, 8),  256, 0, stream>>>(sig, w1, b1, r1);
  k2n_p16     <<<dim3(32, 16), 256, 0, stream>>>(r1, w2, b2, flat);
  k3_linear_nt<<<dim3(32, 32), 256, 0, stream>>>(lw, flat, partials);
  k4_hdc      <<<dim3(157, 1), 64,  0, stream>>>(partials, lb, hw, hb,
                                                 feat, fidx, fw, fb, out);
}

// Round 10
// 97.487 us; speedup vs baseline: 14.9819x; 3.5393x over previous
//
#include <hip/hip_runtime.h>
#include <math.h>

// ---- problem geometry ----
#define T_IN    8192
#define T1      8183        // conv1 'valid' output length
#define LP      4087        // after MaxPool1d(2)
#define NFLAT   523136      // 128 * 4087
#define NFLAT4  130784      // NFLAT / 4
#define NDIM    10000
#define RSTRIDE 8208        // padded row stride for r1
#define F_OFF   (64*RSTRIDE)     // start of flat[] in ws (floats)
#define P_OFF   (F_OFF + NFLAT)  // start of partials[128][32] in ws
#define NCHUNK  32
#define CHUNK4  4087        // float4 per chunk (NFLAT4 / 32)
#define NTROWS  32          // k3: rows 0..31 NT-streamed (67 MB); 32..127 MALL-resident (201 MB)

typedef __attribute__((ext_vector_type(4))) float f4;

// =====================================================================
// Kernel 1: conv1 (round-3 exact)
// =====================================================================
__global__ __launch_bounds__(256) void k1_conv1(
    const float* __restrict__ sig, const float* __restrict__ w1,
    const float* __restrict__ b1, float* __restrict__ r1)
{
  __shared__ float4 srow[266];
  const int tid = threadIdx.x;
  const int t0b = blockIdx.x * 256;
  for (int idx = tid; idx < 266; idx += 256) {
    int t = t0b + idx;
    float4 v = make_float4(0.f, 0.f, 0.f, 0.f);
    if (t < T_IN) v = ((const float4*)sig)[t];
    srow[idx] = v;
  }
  __syncthreads();
  const int t = t0b + tid;
  float s[40];
#pragma unroll
  for (int k = 0; k < 10; ++k) {
    float4 v = srow[tid + k];
    s[4*k+0] = v.x; s[4*k+1] = v.y; s[4*k+2] = v.z; s[4*k+3] = v.w;
  }
  const int c0 = blockIdx.y * 8;
  for (int c = c0; c < c0 + 8; ++c) {
    const float* __restrict__ w = w1 + c * 40;
    float a0 = 0.f, a1 = 0.f, a2 = 0.f, a3 = 0.f;
#pragma unroll
    for (int k = 0; k < 10; ++k) {
      a0 = fmaf(s[4*k+0], w[k     ], a0);
      a1 = fmaf(s[4*k+1], w[10 + k], a1);
      a2 = fmaf(s[4*k+2], w[20 + k], a2);
      a3 = fmaf(s[4*k+3], w[30 + k], a3);
    }
    float v = fmaxf((a0 + a1) + (a2 + a3) + b1[c], 0.f);
    if (t < T1) r1[c * RSTRIDE + t] = v;
  }
}

// =====================================================================
// Kernel 2: conv2+pool, LDS-free (round-9 body, rep=1), grid (32,32):
// 1 output channel per wave -> 1024 blocks = 4/CU = 16 waves/CU (2x the
// round-9 probe's TLP; probe showed 40% latency stall at 2 blocks/CU).
// r1 window read directly from L2-resident r1 via 4 coalesced dwordx4.
// Per-output (c asc, k asc) accumulation order -> bit-exact flat[].
// =====================================================================
__global__ __launch_bounds__(256) void k2_conv2pool(
    const float* __restrict__ r1, const float* __restrict__ w2,
    const float* __restrict__ b2, float* __restrict__ flat)
{
  const int tid  = threadIdx.x;
  const int lane = tid & 63;
  const int wave = tid >> 6;
  const int t0b  = blockIdx.x * 256;
  const int o    = __builtin_amdgcn_readfirstlane(blockIdx.y * 4 + wave);
  const int t0   = t0b + lane * 4;

  float acc[4] = {0.f, 0.f, 0.f, 0.f};

  for (int c = 0; c < 64; ++c) {
    const f4* __restrict__ p = (const f4*)(r1 + c * RSTRIDE + t0b) + lane;
    f4 v0 = p[0];          // floats t0 .. t0+3   (consecutive lanes -> coalesced)
    f4 v1 = p[1];          // t0+4 .. t0+7
    f4 v2 = p[2];          // t0+8 .. t0+11
    f4 v3 = p[3];          // t0+12.. t0+15 (f[13..15] dead; stays in padded row)
    float f[16];
    f[0]=v0.x; f[1]=v0.y; f[2]=v0.z; f[3]=v0.w;
    f[4]=v1.x; f[5]=v1.y; f[6]=v1.z; f[7]=v1.w;
    f[8]=v2.x; f[9]=v2.y; f[10]=v2.z; f[11]=v2.w;
    f[12]=v3.x; f[13]=v3.y; f[14]=v3.z; f[15]=v3.w;
    const float* __restrict__ w = w2 + (o * 64 + c) * 10;  // wave-uniform s_loads
#pragma unroll
    for (int k = 0; k < 10; ++k) {
      float wv = w[k];
#pragma unroll
      for (int tt = 0; tt < 4; ++tt)
        acc[tt] = fmaf(wv, f[k + tt], acc[tt]);
    }
  }

  const float bias = b2[o];
#pragma unroll
  for (int lt = 0; lt < 2; ++lt) {
    float a = acc[2*lt]     + bias;
    float b = acc[2*lt + 1] + bias;
    float m = fmaxf(fmaxf(a, b), 0.f);      // relu then pool == pool then relu
    int l = t0 / 2 + lt;
    if (l < LP) flat[o * LP + l] = m;
  }
}

// =====================================================================
// Kernel 3: linear with NT-SPLIT (round-9 exact). Rows 0..31 NT-streamed
// (67 MB, no MALL alloc); rows 32..127 (201 MB) plain -> MALL-resident
// across graph replays. Bit-exact accumulation order.
// =====================================================================
__global__ __launch_bounds__(256) void k3_linear_nt(
    const float* __restrict__ lw, const float* __restrict__ flat,
    float* __restrict__ partials)
{
  const int tid = threadIdx.x;
  const int ch  = blockIdx.x;
  const int j0  = blockIdx.y * 4;
  const f4* __restrict__ fl = (const f4*)flat + (size_t)ch * CHUNK4;
  const bool nt = (j0 < NTROWS);   // block-uniform

  float r[4];
#pragma unroll
  for (int ph = 0; ph < 2; ++ph) {
    const int j = j0 + 2 * ph;
    const f4* __restrict__ p0 = (const f4*)lw + (size_t)(j + 0) * NFLAT4 + (size_t)ch * CHUNK4;
    const f4* __restrict__ p1 = (const f4*)lw + (size_t)(j + 1) * NFLAT4 + (size_t)ch * CHUNK4;
    f4 a0 = (f4)0.f, a1 = (f4)0.f;
    if (nt) {
      for (int i = tid; i < CHUNK4; i += 256) {
        f4 x  = fl[i];
        f4 w0 = __builtin_nontemporal_load(p0 + i);
        f4 w1 = __builtin_nontemporal_load(p1 + i);
        a0.x = fmaf(x.x, w0.x, a0.x); a0.y = fmaf(x.y, w0.y, a0.y);
        a0.z = fmaf(x.z, w0.z, a0.z); a0.w = fmaf(x.w, w0.w, a0.w);
        a1.x = fmaf(x.x, w1.x, a1.x); a1.y = fmaf(x.y, w1.y, a1.y);
        a1.z = fmaf(x.z, w1.z, a1.z); a1.w = fmaf(x.w, w1.w, a1.w);
      }
    } else {
      for (int i = tid; i < CHUNK4; i += 256) {
        f4 x  = fl[i];
        f4 w0 = p0[i];
        f4 w1 = p1[i];
        a0.x = fmaf(x.x, w0.x, a0.x); a0.y = fmaf(x.y, w0.y, a0.y);
        a0.z = fmaf(x.z, w0.z, a0.z); a0.w = fmaf(x.w, w0.w, a0.w);
        a1.x = fmaf(x.x, w1.x, a1.x); a1.y = fmaf(x.y, w1.y, a1.y);
        a1.z = fmaf(x.z, w1.z, a1.z); a1.w = fmaf(x.w, w1.w, a1.w);
      }
    }
    r[2*ph + 0] = (a0.x + a0.y) + (a0.z + a0.w);
    r[2*ph + 1] = (a1.x + a1.y) + (a1.z + a1.w);
  }

  __shared__ float red[4][257];
#pragma unroll
  for (int j = 0; j < 4; ++j) red[j][tid] = r[j];
  for (int off = 128; off > 0; off >>= 1) {
    __syncthreads();
    if (tid < off) {
#pragma unroll
      for (int j = 0; j < 4; ++j) red[j][tid] += red[j][tid + off];
    }
  }
  if (tid == 0) {
#pragma unroll
    for (int j = 0; j < 4; ++j) partials[(j0 + j) * NCHUNK + ch] = red[j][0];
  }
}

// =====================================================================
// Kernel 4: finalize (round-3 exact)
// =====================================================================
__global__ __launch_bounds__(64) void k4_hdc(
    const float* __restrict__ partials, const float* __restrict__ lin_b,
    const float* __restrict__ hdc_w, const float* __restrict__ hdc_b,
    const float* __restrict__ feat, const int* __restrict__ feat_idx,
    const float* __restrict__ feat_w, const float* __restrict__ feat_b,
    float* __restrict__ out)
{
  __shared__ __align__(16) float y[128];
  __shared__ float fv[18];
  const int tid = threadIdx.x;
#pragma unroll
  for (int half = 0; half < 2; ++half) {
    const int row = tid + half * 64;
    float s = lin_b[row];
    const float* p = partials + row * NCHUNK;
#pragma unroll
    for (int c = 0; c < NCHUNK; ++c) s += p[c];
    y[row] = fmaxf(s, 0.f);
  }
  if (tid < 18) fv[tid] = feat[feat_idx[tid]];
  __syncthreads();

  const int d = blockIdx.x * 64 + tid;
  if (d >= NDIM) return;

  const float4* __restrict__ hw = (const float4*)(hdc_w + d * 128);
  const float4* __restrict__ yy = (const float4*)y;
  float4 ac = make_float4(0, 0, 0, 0);
#pragma unroll
  for (int q = 0; q < 32; ++q) {
    float4 w = hw[q];
    float4 v = yy[q];
    ac.x = fmaf(w.x, v.x, ac.x); ac.y = fmaf(w.y, v.y, ac.y);
    ac.z = fmaf(w.z, v.z, ac.z); ac.w = fmaf(w.w, v.w, ac.w);
  }
  const float proj = (ac.x + ac.y) + (ac.z + ac.w);
  const float sample_hv = cosf(proj + hdc_b[d]) * sinf(proj);

  float h[18];
#pragma unroll
  for (int i = 0; i < 18; ++i) {
    float fp = fv[i] * feat_w[i * NDIM + d];
    h[i] = cosf(fp + feat_b[i * NDIM + d]) * sinf(fp);
  }
  const float feat_hv =
      (h[14] + h[11]) * h[16]
    * (h[4] + h[8] + h[6] + h[1] + h[5] + h[12] + h[17])
    * h[13] * (h[15] + h[2]) * h[3]
    * h[0] * h[10] * h[7] * h[9];

  const float comb = sample_hv + feat_hv;
  out[d] = comb > 0.f ? 1.f : -1.f;
}

// =====================================================================
extern "C" void kernel_launch(void* const* d_in, const int* in_sizes, int n_in,
                              void* d_out, int out_size, void* d_ws, size_t ws_size,
                              hipStream_t stream)
{
  const float* sig  = (const float*)d_in[0];
  const float* feat = (const float*)d_in[1];
  const float* w1   = (const float*)d_in[2];
  const float* b1   = (const float*)d_in[3];
  const float* w2   = (const float*)d_in[4];
  const float* b2   = (const float*)d_in[5];
  const float* lw   = (const float*)d_in[6];
  const float* lb   = (const float*)d_in[7];
  const float* hw   = (const float*)d_in[8];
  const float* hb   = (const float*)d_in[9];
  const float* fw   = (const float*)d_in[10];
  const float* fb   = (const float*)d_in[11];
  const int*   fidx = (const int*)d_in[12];
  float* out = (float*)d_out;
  float* ws  = (float*)d_ws;

  float* r1       = ws;              // [64][RSTRIDE]
  float* flat     = ws + F_OFF;      // [NFLAT]
  float* partials = ws + P_OFF;      // [128][NCHUNK]

  k1_conv1    <<<dim3(32, 8),  256, 0, stream>>>(sig, w1, b1, r1);
  k2_conv2pool<<<dim3(32, 32), 256, 0, stream>>>(r1, w2, b2, flat);
  k3_linear_nt<<<dim3(32, 32), 256, 0, stream>>>(lw, flat, partials);
  k4_hdc      <<<dim3(157, 1), 64,  0, stream>>>(partials, lb, hw, hb,
                                                 feat, fidx, fw, fb, out);
}

// Round 11
// 95.443 us; speedup vs baseline: 15.3028x; 1.0214x over previous
//
#include <hip/hip_runtime.h>
#include <math.h>

// ---- problem geometry ----
#define T_IN    8192
#define T1      8183        // conv1 'valid' output length
#define LP      4087        // after MaxPool1d(2)
#define NFLAT   523136      // 128 * 4087
#define NFLAT4  130784      // NFLAT / 4
#define NDIM    10000
#define RSTRIDE 8208        // padded row stride for r1
#define F_OFF   (64*RSTRIDE)     // start of flat[] in ws (floats)
#define P_OFF   (F_OFF + NFLAT)  // start of partials[128][32] in ws
#define NCHUNK  32
#define CHUNK4  4087        // float4 per chunk (NFLAT4 / 32)

typedef __attribute__((ext_vector_type(4))) float f4;

// =====================================================================
// Kernel 1: conv1 (round-3 exact; ~2 us measured via round-7 probe)
// =====================================================================
__global__ __launch_bounds__(256) void k1_conv1(
    const float* __restrict__ sig, const float* __restrict__ w1,
    const float* __restrict__ b1, float* __restrict__ r1)
{
  __shared__ float4 srow[266];
  const int tid = threadIdx.x;
  const int t0b = blockIdx.x * 256;
  for (int idx = tid; idx < 266; idx += 256) {
    int t = t0b + idx;
    float4 v = make_float4(0.f, 0.f, 0.f, 0.f);
    if (t < T_IN) v = ((const float4*)sig)[t];
    srow[idx] = v;
  }
  __syncthreads();
  const int t = t0b + tid;
  float s[40];
#pragma unroll
  for (int k = 0; k < 10; ++k) {
    float4 v = srow[tid + k];
    s[4*k+0] = v.x; s[4*k+1] = v.y; s[4*k+2] = v.z; s[4*k+3] = v.w;
  }
  const int c0 = blockIdx.y * 8;
  for (int c = c0; c < c0 + 8; ++c) {
    const float* __restrict__ w = w1 + c * 40;
    float a0 = 0.f, a1 = 0.f, a2 = 0.f, a3 = 0.f;
#pragma unroll
    for (int k = 0; k < 10; ++k) {
      a0 = fmaf(s[4*k+0], w[k     ], a0);
      a1 = fmaf(s[4*k+1], w[10 + k], a1);
      a2 = fmaf(s[4*k+2], w[20 + k], a2);
      a3 = fmaf(s[4*k+3], w[30 + k], a3);
    }
    float v = fmaxf((a0 + a1) + (a2 + a3) + b1[c], 0.f);
    if (t < T1) r1[c * RSTRIDE + t] = v;
  }
}

// =====================================================================
// Kernel 2: conv2+pool, LDS-free, 2 ch/wave (round-9 probe config, rep=1:
// 20.0 us profiled, SQ_LDS_BANK_CONFLICT=0, VALUBusy 60%). grid (32,16)
// = 512 blocks = 8 waves/CU. Window loads amortized over 2 channels
// (round-10's 1 ch/wave doubled load count -> ~30 us; reverted).
// Per-output (c asc, k asc) order -> bit-exact flat[].
// =====================================================================
__global__ __launch_bounds__(256) void k2_conv2pool(
    const float* __restrict__ r1, const float* __restrict__ w2,
    const float* __restrict__ b2, float* __restrict__ flat)
{
  const int tid  = threadIdx.x;
  const int lane = tid & 63;
  const int wave = tid >> 6;
  const int t0b  = blockIdx.x * 256;
  const int o0   = __builtin_amdgcn_readfirstlane(blockIdx.y * 8 + wave * 2);
  const int t0   = t0b + lane * 4;

  float acc[2][4];
#pragma unroll
  for (int a = 0; a < 2; ++a)
#pragma unroll
    for (int b = 0; b < 4; ++b) acc[a][b] = 0.f;

  for (int c = 0; c < 64; ++c) {
    const f4* __restrict__ p = (const f4*)(r1 + c * RSTRIDE + t0b) + lane;
    f4 v0 = p[0];          // floats t0 .. t0+3   (consecutive lanes -> coalesced)
    f4 v1 = p[1];          // t0+4 .. t0+7
    f4 v2 = p[2];          // t0+8 .. t0+11
    f4 v3 = p[3];          // t0+12.. t0+15 (f[13..15] dead; stays in padded row)
    float f[16];
    f[0]=v0.x; f[1]=v0.y; f[2]=v0.z; f[3]=v0.w;
    f[4]=v1.x; f[5]=v1.y; f[6]=v1.z; f[7]=v1.w;
    f[8]=v2.x; f[9]=v2.y; f[10]=v2.z; f[11]=v2.w;
    f[12]=v3.x; f[13]=v3.y; f[14]=v3.z; f[15]=v3.w;
#pragma unroll
    for (int oo = 0; oo < 2; ++oo) {
      const float* __restrict__ w = w2 + ((o0 + oo) * 64 + c) * 10; // wave-uniform s_loads
#pragma unroll
      for (int k = 0; k < 10; ++k) {
        float wv = w[k];
#pragma unroll
        for (int tt = 0; tt < 4; ++tt)
          acc[oo][tt] = fmaf(wv, f[k + tt], acc[oo][tt]);
      }
    }
  }

#pragma unroll
  for (int oo = 0; oo < 2; ++oo) {
    const int o = o0 + oo;
    const float bias = b2[o];
#pragma unroll
    for (int lt = 0; lt < 2; ++lt) {
      float a = acc[oo][2*lt]     + bias;
      float b = acc[oo][2*lt + 1] + bias;
      float m = fmaxf(fmaxf(a, b), 0.f);      // relu then pool == pool then relu
      int l = t0 / 2 + lt;
      if (l < LP) flat[o * LP + l] = m;
    }
  }
}

// =====================================================================
// Kernel 3: linear, PLAIN loads (round-3 exact; 37.5 us measured --
// at the HBM floor given the harness's inter-replay 1 GB fills flush
// MALL; NT variants are neutral-to-worse, reverted).
// =====================================================================
__global__ __launch_bounds__(256) void k3_linear(
    const float* __restrict__ lw, const float* __restrict__ flat,
    float* __restrict__ partials)
{
  const int tid = threadIdx.x;
  const int ch  = blockIdx.x;
  const int j0  = blockIdx.y * 4;
  const f4* __restrict__ fl = (const f4*)flat + (size_t)ch * CHUNK4;

  float r[4];
#pragma unroll
  for (int ph = 0; ph < 2; ++ph) {
    const int j = j0 + 2 * ph;
    const f4* __restrict__ p0 = (const f4*)lw + (size_t)(j + 0) * NFLAT4 + (size_t)ch * CHUNK4;
    const f4* __restrict__ p1 = (const f4*)lw + (size_t)(j + 1) * NFLAT4 + (size_t)ch * CHUNK4;
    f4 a0 = (f4)0.f, a1 = (f4)0.f;
    for (int i = tid; i < CHUNK4; i += 256) {
      f4 x  = fl[i];
      f4 w0 = p0[i];
      f4 w1 = p1[i];
      a0.x = fmaf(x.x, w0.x, a0.x); a0.y = fmaf(x.y, w0.y, a0.y);
      a0.z = fmaf(x.z, w0.z, a0.z); a0.w = fmaf(x.w, w0.w, a0.w);
      a1.x = fmaf(x.x, w1.x, a1.x); a1.y = fmaf(x.y, w1.y, a1.y);
      a1.z = fmaf(x.z, w1.z, a1.z); a1.w = fmaf(x.w, w1.w, a1.w);
    }
    r[2*ph + 0] = (a0.x + a0.y) + (a0.z + a0.w);
    r[2*ph + 1] = (a1.x + a1.y) + (a1.z + a1.w);
  }

  __shared__ float red[4][257];
#pragma unroll
  for (int j = 0; j < 4; ++j) red[j][tid] = r[j];
  for (int off = 128; off > 0; off >>= 1) {
    __syncthreads();
    if (tid < off) {
#pragma unroll
      for (int j = 0; j < 4; ++j) red[j][tid] += red[j][tid + off];
    }
  }
  if (tid == 0) {
#pragma unroll
    for (int j = 0; j < 4; ++j) partials[(j0 + j) * NCHUNK + ch] = red[j][0];
  }
}

// =====================================================================
// Kernel 4: finalize (round-3 exact; ~3.5 us measured via round-7 probe)
// =====================================================================
__global__ __launch_bounds__(64) void k4_hdc(
    const float* __restrict__ partials, const float* __restrict__ lin_b,
    const float* __restrict__ hdc_w, const float* __restrict__ hdc_b,
    const float* __restrict__ feat, const int* __restrict__ feat_idx,
    const float* __restrict__ feat_w, const float* __restrict__ feat_b,
    float* __restrict__ out)
{
  __shared__ __align__(16) float y[128];
  __shared__ float fv[18];
  const int tid = threadIdx.x;
#pragma unroll
  for (int half = 0; half < 2; ++half) {
    const int row = tid + half * 64;
    float s = lin_b[row];
    const float* p = partials + row * NCHUNK;
#pragma unroll
    for (int c = 0; c < NCHUNK; ++c) s += p[c];
    y[row] = fmaxf(s, 0.f);
  }
  if (tid < 18) fv[tid] = feat[feat_idx[tid]];
  __syncthreads();

  const int d = blockIdx.x * 64 + tid;
  if (d >= NDIM) return;

  const float4* __restrict__ hw = (const float4*)(hdc_w + d * 128);
  const float4* __restrict__ yy = (const float4*)y;
  float4 ac = make_float4(0, 0, 0, 0);
#pragma unroll
  for (int q = 0; q < 32; ++q) {
    float4 w = hw[q];
    float4 v = yy[q];
    ac.x = fmaf(w.x, v.x, ac.x); ac.y = fmaf(w.y, v.y, ac.y);
    ac.z = fmaf(w.z, v.z, ac.z); ac.w = fmaf(w.w, v.w, ac.w);
  }
  const float proj = (ac.x + ac.y) + (ac.z + ac.w);
  const float sample_hv = cosf(proj + hdc_b[d]) * sinf(proj);

  float h[18];
#pragma unroll
  for (int i = 0; i < 18; ++i) {
    float fp = fv[i] * feat_w[i * NDIM + d];
    h[i] = cosf(fp + feat_b[i * NDIM + d]) * sinf(fp);
  }
  const float feat_hv =
      (h[14] + h[11]) * h[16]
    * (h[4] + h[8] + h[6] + h[1] + h[5] + h[12] + h[17])
    * h[13] * (h[15] + h[2]) * h[3]
    * h[0] * h[10] * h[7] * h[9];

  const float comb = sample_hv + feat_hv;
  out[d] = comb > 0.f ? 1.f : -1.f;
}

// =====================================================================
extern "C" void kernel_launch(void* const* d_in, const int* in_sizes, int n_in,
                              void* d_out, int out_size, void* d_ws, size_t ws_size,
                              hipStream_t stream)
{
  const float* sig  = (const float*)d_in[0];
  const float* feat = (const float*)d_in[1];
  const float* w1   = (const float*)d_in[2];
  const float* b1   = (const float*)d_in[3];
  const float* w2   = (const float*)d_in[4];
  const float* b2   = (const float*)d_in[5];
  const float* lw   = (const float*)d_in[6];
  const float* lb   = (const float*)d_in[7];
  const float* hw   = (const float*)d_in[8];
  const float* hb   = (const float*)d_in[9];
  const float* fw   = (const float*)d_in[10];
  const float* fb   = (const float*)d_in[11];
  const int*   fidx = (const int*)d_in[12];
  float* out = (float*)d_out;
  float* ws  = (float*)d_ws;

  float* r1       = ws;              // [64][RSTRIDE]
  float* flat     = ws + F_OFF;      // [NFLAT]
  float* partials = ws + P_OFF;      // [128][NCHUNK]

  k1_conv1    <<<dim3(32, 8),  256, 0, stream>>>(sig, w1, b1, r1);
  k2_conv2pool<<<dim3(32, 16), 256, 0, stream>>>(r1, w2, b2, flat);
  k3_linear   <<<dim3(32, 32), 256, 0, stream>>>(lw, flat, partials);
  k4_hdc      <<<dim3(157, 1), 64,  0, stream>>>(partials, lb, hw, hb,
                                                 feat, fidx, fw, fb, out);
}